// Round 8
// baseline (968.325 us; speedup 1.0000x reference)
//
#include <hip/hip_runtime.h>

#define LL    1024
#define NB    8
#define NT    256          // 4 waves per WG
#define KCH   16           // steps per chunk (one barrier per chunk)
#define SKEW  96           // intra-WG wave skew = 64 rows + KCH + 16 margin
#define SBMAX 1072         // last chunk-start; covers local steps up to 1087
#define NCH   86           // c in [0, 85]; wave 3 last active sb = 16*85-288 = 1072
#define YTN   1536         // y-table entries (float2)
#define BROW  1160         // bndX row stride (floats)
#define BOFF  128          // col 0 of a boundary row at index BOFF
#define GBASE 64           // d_ws float offset of link regions
#define GSTR  1280         // per-link region stride (floats)
#define GDUMP (GBASE + 24 * GSTR)   // dump scratch (>= 128 floats)
#define C10   14.426950408889634f        // 10*log2(e)
#define CLOG  (-0.069314718055994531f)   // -(ln2)/10
#define EPS3  1e-12f

// Soft-DTW in e-space (e = exp(-10*D)); 16 strips x 64 rows across 4 WGs/batch.
// Lane l owns one row; up/diag neighbor via wave_shr:1 DPP (no LDS round-trip).
// Intra-WG handoff: LDS boundary rows, window prefetched one chunk early.
// Inter-WG handoff: producer lane 63 stores each boundary value per-step via
// relaxed agent-scope atomics; consumer prefetches one chunk ahead, validates
// by sentinel (< 0), with full backstop sweep at end (round-6/7 proven).

#define YB4(k) ((((k) >> 3) & 1)                                               \
    ? (((((k) & 7) >> 1) == 0) ? Bv0 : ((((k) & 7) >> 1) == 1) ? Bv1           \
                               : ((((k) & 7) >> 1) == 2) ? Bv2 : Bv3)          \
    : (((((k) & 7) >> 1) == 0) ? Av0 : ((((k) & 7) >> 1) == 1) ? Av1           \
                               : ((((k) & 7) >> 1) == 2) ? Av2 : Av3))
#define FPE(k) (((k) & 1) ? YB4(k).z : YB4(k).x)
#define FNE(k) (((k) & 1) ? YB4(k).w : YB4(k).y)

// Cell (lane+1, j) at local step s = lane + j; entry ji = s - lane + 256.
#define STEPBODY(r, EXTRA) do {                                                \
    const float fp_ = FPE(r);                                                  \
    const float fn_ = FNE(r);                                                  \
    const float dppv_ = __int_as_float(__builtin_amdgcn_update_dpp(            \
        0, __float_as_int(E1), 0x138, 0xf, 0xf, true)); /* wave_shr:1 */       \
    const float bvs_ = __int_as_float(                                         \
        __builtin_amdgcn_readlane(__float_as_int(Bv), (r)));                   \
    const float upa_ = isL0 ? bvs_ : dppv_;                                    \
    const float eca_ = fminf(EN0 * fp_, EP0 * fn_);                            \
    const float mma_ = fmaf(up_del + E1 + upa_, (1.f / 3.f), EPS3);            \
    const float nva_ = eca_ * mma_;                                            \
    wbase[(r)] = nva_;                                                         \
    EXTRA                                                                      \
    E1 = nva_; up_del = upa_; lastmm = mma_;                                   \
  } while (0)

#define STEP(r)  STEPBODY(r, )
#define STEPP(r) STEPBODY(r, __hip_atomic_store(gsk + (r), __float_as_int(nva_), \
                              __ATOMIC_RELAXED, __HIP_MEMORY_SCOPE_AGENT);)

#define DO16(M)  M(0); M(1); M(2); M(3); M(4); M(5); M(6); M(7);               \
                 M(8); M(9); M(10); M(11); M(12); M(13); M(14); M(15)

#define LD4(d0, d1, d2, d3, byteoff) do {                                      \
    const char* p_ = ytp + (byteoff);                                          \
    d0 = *(const float4*)(p_);                                                 \
    d1 = *(const float4*)(p_ + 16);                                            \
    d2 = *(const float4*)(p_ + 32);                                            \
    d3 = *(const float4*)(p_ + 48);                                            \
  } while (0)

__global__ __launch_bounds__(NT, 1) void dtw_kernel(const float* __restrict__ outp,
                                                    const float* __restrict__ tgtp,
                                                    float* __restrict__ wsf) {
  const int bb = blockIdx.x >> 2;      // batch
  const int wg = blockIdx.x & 3;       // quarter: rows 256*wg+1 .. 256*wg+256
  const int t = threadIdx.x;
  const int lane = t & 63;
  const int wvs = __builtin_amdgcn_readfirstlane(t >> 6);

  __shared__ float2 ytabA[YTN];       // (fp,fn) at slot ji        (even lanes)
  __shared__ float2 ytabB[YTN];       // (fp,fn) at slot ji - 1    (odd lanes)
  __shared__ float  bndX[5][BROW];    // 0-2: waves 0-2 boundaries; 3: zeros+seed; 4: wave-3 staging
  __shared__ float  dumpA[4][128];    // LDS sink for non-lane-63 staging writes

  {
    float4* za = (float4*)&ytabA[0];
    for (int i = t; i < (YTN * 2) / 4; i += NT) za[i] = make_float4(0.f, 0.f, 0.f, 0.f);
    float4* zb2 = (float4*)&ytabB[0];
    for (int i = t; i < (YTN * 2) / 4; i += NT) zb2[i] = make_float4(0.f, 0.f, 0.f, 0.f);
    float4* zb = (float4*)&bndX[0][0];
    for (int i = t; i < (5 * BROW) / 4; i += NT) zb[i] = make_float4(0.f, 0.f, 0.f, 0.f);
  }
  __syncthreads();

  const float* xb = outp + (size_t)bb * LL * LL;
  const float* yb = tgtp + (size_t)bb * LL * LL;

  // my row: global row 256*wg + 64*wvs + lane + 1
  const float xd = xb[256 * wg + 64 * wvs + lane];
  const float EP0 = __builtin_amdgcn_exp2f( C10 * xd);
  const float EN0 = __builtin_amdgcn_exp2f(-C10 * xd);

  {
    const float4 yv = *(const float4*)(yb + 4 * t);
    const float yy[4] = {yv.x, yv.y, yv.z, yv.w};
#pragma unroll
    for (int q = 0; q < 4; ++q) {
      const int ji = (4 * t + 1 + q) + 256;          // j in [1,1024]
      const float2 v = make_float2(__builtin_amdgcn_exp2f( C10 * yy[q]),
                                   __builtin_amdgcn_exp2f(-C10 * yy[q]));
      ytabA[ji] = v;
      ytabB[ji - 1] = v;
    }
  }
  if (wg == 0 && t == 0) bndX[3][BOFF] = 1.0f;      // e[0,0] = 1 seed
  const float costL = (wg == 3 && t == NT - 1) ? fabsf(xd - yb[LL - 1]) : 0.f;
  __syncthreads();

  float E1 = 0.f, up_del = 0.f, lastmm = EPS3;
  float4 Av0, Av1, Av2, Av3;
  float4 Bv0 = make_float4(0.f, 0.f, 0.f, 0.f), Bv1 = Bv0, Bv2 = Bv0, Bv3 = Bv0;
  Av0 = Bv0; Av1 = Bv0; Av2 = Bv0; Av3 = Bv0;
  const bool isL0 = (lane == 0);
  const int wprev = (wvs == 0) ? 3 : (wvs - 1);
  const int wwr   = (wvs == 3) ? 4 : wvs;
  const bool isProd = (wg < 3) && (wvs == 3);
  const bool isCons = (wg > 0) && (wvs == 0);
  // per-lane y-table view: 16B-aligned for every lane via the dual table
  const char* ytp = (lane & 1) ? (const char*)ytabB : (const char*)ytabA;
  const int   loff = 8 * (((lane & 1) ? 255 : 256) - lane);

  float* gprod = wsf + GBASE + (bb * 3 + wg)     * GSTR + 128;  // valid when wg<3
  float* gcons = wsf + GBASE + (bb * 3 + wg - 1) * GSTR + 128;  // valid when wg>0
  int*   dumpG = (int*)(wsf + GDUMP);

  float Bv = 0.f;
  int*  pcurB = dumpG;
  if (wvs == 0) {
    if (isCons) {
      // sentinel-fill cols 1..1024 (col 0 handled by register override)
      for (int c0 = lane; c0 <= LL; c0 += 64)
        if (c0 >= 1)
          __hip_atomic_store((int*)(gcons + c0), __float_as_int(-1.0f),
                             __ATOMIC_RELAXED, __HIP_MEMORY_SCOPE_AGENT);
      __threadfence();
      pcurB = (int*)(gcons + lane);
      Bv = __int_as_float(__hip_atomic_load(pcurB, __ATOMIC_RELAXED,
                                            __HIP_MEMORY_SCOPE_AGENT));
      if (isL0) Bv = 0.f;                  // col 0 border: e = 0
    } else {
      Bv = bndX[wprev][lane + BOFF];       // wg0: zeros + seed
    }
    LD4(Av0, Av1, Av2, Av3, loff);         // chunk sb=0, entries 0..7
    LD4(Bv0, Bv1, Bv2, Bv3, loff + 64);    // entries 8..15
  }

#pragma unroll 1
  for (int c = 0; c < NCH; ++c) {
    const int sb = KCH * c - SKEW * wvs;   // local step at r=0 (multiple of 16)

    if (sb >= 0 && sb <= SBMAX) {
      if (isCons) {                        // validate prefetched window (lanes 0..15)
        float bv = Bv;
        while (__ballot(bv < 0.f) & 0xffffull) {
          __builtin_amdgcn_s_sleep(2);
          bv = __int_as_float(__hip_atomic_load(pcurB, __ATOMIC_RELAXED,
                                                __HIP_MEMORY_SCOPE_AGENT));
          if (isL0 && sb == 0) bv = 0.f;
        }
        Bv = bv;
      }
      // staging: lane 63 -> boundary row (col sb+r-63 at index sb+65+r), else sink
      float* wbase = (lane == 63) ? &bndX[wwr][sb + 65] : &dumpA[wvs][lane];
      if (isProd) {
        int* gsk = (lane == 63 && sb >= 64) ? (int*)(gprod + (sb - 63))
                                            : (dumpG + lane);
        DO16(STEPP);
      } else {
        DO16(STEP);
      }
    }

    // prefetch next chunk (ytab is read-only; bndX early-read safe at SKEW=96)
    const int sbn = sb + KCH;
    if (sbn >= 0 && sbn <= SBMAX) {
      const int baseN = loff + 8 * sbn;
      LD4(Av0, Av1, Av2, Av3, baseN);
      LD4(Bv0, Bv1, Bv2, Bv3, baseN + 64);
      if (isCons) {
        int cn = sbn + lane; cn = cn > LL ? LL : cn;
        pcurB = (int*)(gcons + cn);
        Bv = __int_as_float(__hip_atomic_load(pcurB, __ATOMIC_RELAXED,
                                              __HIP_MEMORY_SCOPE_AGENT));
      } else {
        int colp = sbn + lane; colp = colp > LL ? LL : colp;
        Bv = bndX[wprev][colp + BOFF];
      }
    }
    __syncthreads();
  }

  if (isProd) {   // backstop: full boundary-row sweep (correctness safety net)
    for (int c0 = lane; c0 <= LL; c0 += 64)
      if (c0 >= 1)
        __hip_atomic_store((int*)(gprod + c0), __float_as_int(bndX[4][c0 + BOFF]),
                           __ATOMIC_RELAXED, __HIP_MEMORY_SCOPE_AGENT);
  }

  // final cell (1024,1024): WG3 wave 3 lane 63 at s = 1087 (chunk sb=1072, r=15)
  if (wg == 3 && t == NT - 1) wsf[bb] = costL + CLOG * __builtin_amdgcn_logf(lastmm);
}

__global__ void reduce_mean(const float* __restrict__ ws, float* __restrict__ out) {
  if (threadIdx.x == 0 && blockIdx.x == 0) {
    float s = 0.f;
    for (int i = 0; i < NB; ++i) s += ws[i];
    out[0] = s * (1.0f / NB);
  }
}

extern "C" void kernel_launch(void* const* d_in, const int* in_sizes, int n_in,
                              void* d_out, int out_size, void* d_ws, size_t ws_size,
                              hipStream_t stream) {
  const float* o  = (const float*)d_in[0];
  const float* tg = (const float*)d_in[1];
  float* ws  = (float*)d_ws;
  float* out = (float*)d_out;

  dtw_kernel<<<4 * NB, NT, 0, stream>>>(o, tg, ws);
  reduce_mean<<<1, 64, 0, stream>>>(ws, out);
}

// Round 9
// 102.766 us; speedup vs baseline: 9.4226x; 9.4226x over previous
//
#include <hip/hip_runtime.h>

#define LL    1024
#define NB    8
#define NT    256          // 4 waves per WG
#define KCH   32           // steps per chunk (one barrier per chunk)
#define SKEW  96           // intra-WG wave skew = 64 rows + KCH (exact-tight)
#define SBMAX 1056         // last chunk start (covers local steps up to 1087)
#define NCH   43           // wave 3 last active chunk: (1056+288)/32 = 42
#define YTN   1536         // y-table entries (float2) per table
#define BROW  1160         // bndX row stride (floats)
#define BOFF  128          // col 0 of a boundary row at index BOFF
#define GBASE 64           // d_ws float offset of link regions
#define GSTR  1280         // per-link region stride (floats)
#define C10   14.426950408889634f        // 10*log2(e)
#define CLOG  (-0.069314718055994531f)   // -(ln2)/10
#define EPS3  1e-12f

// Soft-DTW in e-space (e = exp(-10*D)); 16 strips x 64 rows across 4 WGs/batch.
// Round 9 = round-7 base (92.5us, chunked inter-WG export — round 8's per-step
// export regressed 10x) + (a) XOR-swizzled y-tables (bank-conflict-free LD4),
// (b) LD4s software-pipelined across the barrier, (c) chunk-tail export window.

#define SWZ(o) ((o) ^ ((((o) >> 7) & 7) << 4))   // T2 swizzle: bits4-6 ^= bits7-9

#define YB4(k) ((((k) >> 3) & 1)                                               \
    ? (((((k) & 7) >> 1) == 0) ? Bv0 : ((((k) & 7) >> 1) == 1) ? Bv1           \
                               : ((((k) & 7) >> 1) == 2) ? Bv2 : Bv3)          \
    : (((((k) & 7) >> 1) == 0) ? Av0 : ((((k) & 7) >> 1) == 1) ? Av1           \
                               : ((((k) & 7) >> 1) == 2) ? Av2 : Av3))
#define FPE(k) (((k) & 1) ? YB4(k).z : YB4(k).x)
#define FNE(k) (((k) & 1) ? YB4(k).w : YB4(k).y)

// Cell (lane+1, j) at local step s = lane + j; entry ji = s - lane + 256.
#define STEP(r) do {                                                           \
    const float fp_ = FPE(r);                                                  \
    const float fn_ = FNE(r);                                                  \
    const float dppv_ = __int_as_float(__builtin_amdgcn_update_dpp(            \
        0, __float_as_int(E1), 0x138, 0xf, 0xf, true)); /* wave_shr:1 */       \
    const float bvs_ = __int_as_float(                                         \
        __builtin_amdgcn_readlane(__float_as_int(B), (r)));                    \
    const float upa_ = isL0 ? bvs_ : dppv_;                                    \
    const float eca_ = fminf(EN0 * fp_, EP0 * fn_);                            \
    const float mma_ = fmaf(up_del + E1 + upa_, (1.f / 3.f), EPS3);            \
    const float nva_ = eca_ * mma_;                                            \
    wbase[(r)] = nva_;                                                         \
    E1 = nva_; up_del = upa_; lastmm = mma_;                                   \
  } while (0)

#define LD4(d0, d1, d2, d3, byteoff) do {                                      \
    const int b_ = (byteoff);                                                  \
    d0 = *(const float4*)(ytp + SWZ(b_));                                      \
    d1 = *(const float4*)(ytp + SWZ(b_ + 16));                                 \
    d2 = *(const float4*)(ytp + SWZ(b_ + 32));                                 \
    d3 = *(const float4*)(ytp + SWZ(b_ + 48));                                 \
  } while (0)

__global__ __launch_bounds__(NT, 1) void dtw_kernel(const float* __restrict__ outp,
                                                    const float* __restrict__ tgtp,
                                                    float* __restrict__ wsf) {
  const int bb = blockIdx.x >> 2;      // batch
  const int wg = blockIdx.x & 3;       // quarter: rows 256*wg+1 .. 256*wg+256
  const int t = threadIdx.x;
  const int lane = t & 63;
  const int wvs = __builtin_amdgcn_readfirstlane(t >> 6);

  __shared__ float2 ytabA[YTN];       // swizzled (fp,fn), slot ji     (even lanes)
  __shared__ float2 ytabB[YTN];       // swizzled (fp,fn), slot ji - 1 (odd lanes)
  __shared__ float  bndX[5][BROW];    // 0-2: waves 0-2 boundaries; 3: zeros+seed; 4: wave-3 staging
  __shared__ float  dumpA[4][128];    // LDS sink for non-lane-63 staging writes

  {
    float4* za = (float4*)&ytabA[0];
    for (int i = t; i < (YTN * 2) / 4; i += NT) za[i] = make_float4(0.f, 0.f, 0.f, 0.f);
    float4* zb2 = (float4*)&ytabB[0];
    for (int i = t; i < (YTN * 2) / 4; i += NT) zb2[i] = make_float4(0.f, 0.f, 0.f, 0.f);
    float4* zb = (float4*)&bndX[0][0];
    for (int i = t; i < (5 * BROW) / 4; i += NT) zb[i] = make_float4(0.f, 0.f, 0.f, 0.f);
  }
  __syncthreads();

  const float* xb = outp + (size_t)bb * LL * LL;
  const float* yb = tgtp + (size_t)bb * LL * LL;

  // my row: global row 256*wg + 64*wvs + lane + 1
  const float xd = xb[256 * wg + 64 * wvs + lane];
  const float EP0 = __builtin_amdgcn_exp2f( C10 * xd);
  const float EN0 = __builtin_amdgcn_exp2f(-C10 * xd);

  {
    const float4 yv = *(const float4*)(yb + 4 * t);
    const float yy[4] = {yv.x, yv.y, yv.z, yv.w};
#pragma unroll
    for (int q = 0; q < 4; ++q) {
      const int ji = (4 * t + 1 + q) + 256;          // j in [1,1024]
      const float2 v = make_float2(__builtin_amdgcn_exp2f( C10 * yy[q]),
                                   __builtin_amdgcn_exp2f(-C10 * yy[q]));
      const int o = ji * 8;
      *(float2*)((char*)ytabA + SWZ(o))     = v;
      *(float2*)((char*)ytabB + SWZ(o - 8)) = v;
    }
  }
  if (wg == 0 && t == 0) bndX[3][BOFF] = 1.0f;      // e[0,0] = 1 seed
  const float costL = (wg == 3 && t == NT - 1) ? fabsf(xd - yb[LL - 1]) : 0.f;
  __syncthreads();

  float E1 = 0.f, up_del = 0.f, lastmm = EPS3;
  float4 Av0, Av1, Av2, Av3;
  float4 Bv0 = make_float4(0.f, 0.f, 0.f, 0.f), Bv1 = Bv0, Bv2 = Bv0, Bv3 = Bv0;
  Av0 = Bv0; Av1 = Bv0; Av2 = Bv0; Av3 = Bv0;
  const bool isL0 = (lane == 0);
  const int wprev = (wvs == 0) ? 3 : (wvs - 1);
  const int wwr   = (wvs == 3) ? 4 : wvs;
  const bool isProd = (wg < 3) && (wvs == 3);
  const bool isCons = (wg > 0) && (wvs == 0);
  // per-lane y-table view: 16B-aligned for every lane via the dual table
  const char* ytp = (lane & 1) ? (const char*)ytabB : (const char*)ytabA;
  const int   loff = 8 * (((lane & 1) ? 255 : 256) - lane);

  float* gprod = wsf + GBASE + (bb * 3 + wg)     * GSTR + 128;  // valid when wg<3
  float* gcons = wsf + GBASE + (bb * 3 + wg - 1) * GSTR + 128;  // valid when wg>0

  float Bpre = 0.f;
  int*  pcurB = (int*)gcons;
  if (isCons) {
    // sentinel-fill our link region (robust to any initial / stale d_ws content)
    for (int c0 = lane; c0 <= LL; c0 += 64)
      __hip_atomic_store((int*)(gcons + c0), __float_as_int(-1.0f),
                         __ATOMIC_RELAXED, __HIP_MEMORY_SCOPE_AGENT);
    __threadfence();
  }

#pragma unroll 1
  for (int c = 0; c < NCH; ++c) {
    const int sb = KCH * c - SKEW * wvs;   // local step at r=0 (multiple of 32)

    if (sb >= 0 && sb <= SBMAX) {
      const int base0 = loff + 8 * sb;
      // boundary window for THIS chunk (producer data staged by end of prev chunk)
      float B;
      if (isCons) {
        if (sb == 0) {
          pcurB = (int*)(gcons + lane);
          Bpre = __int_as_float(__hip_atomic_load(pcurB, __ATOMIC_RELAXED,
                                                  __HIP_MEMORY_SCOPE_AGENT));
        }
        float bv = Bpre;
        while (__ballot(bv < 0.f) & 0xffffffffull) {   // lanes 0..31 must be valid
          __builtin_amdgcn_s_sleep(2);
          bv = __int_as_float(__hip_atomic_load(pcurB, __ATOMIC_RELAXED,
                                                __HIP_MEMORY_SCOPE_AGENT));
          if (isL0 && sb == 0) bv = 0.f;               // col 0 border: e = 0
        }
        B = bv;
      } else {
        int colp = sb + lane; colp = colp > LL ? LL : colp;
        B = bndX[wprev][colp + BOFF];
      }
      if (sb == 0) {                      // first active chunk: no prefetch cover
        LD4(Av0, Av1, Av2, Av3, base0);          // g0: entries 0..7
        LD4(Bv0, Bv1, Bv2, Bv3, base0 + 64);     // g1: entries 8..15
      }
      // staging: lane 63 -> boundary row (col sb+r-63 at index sb+65+r), else sink
      float* wbase = (lane == 63) ? &bndX[wwr][sb + 65] : &dumpA[wvs][lane];

      STEP(0); STEP(1); STEP(2); STEP(3); STEP(4); STEP(5); STEP(6); STEP(7);
      LD4(Av0, Av1, Av2, Av3, base0 + 128);      // g2: entries 16..23 (use r=16)
      STEP(8); STEP(9); STEP(10); STEP(11); STEP(12); STEP(13); STEP(14); STEP(15);
      LD4(Bv0, Bv1, Bv2, Bv3, base0 + 192);      // g3: entries 24..31 (use r=24)
      STEP(16); STEP(17); STEP(18); STEP(19); STEP(20); STEP(21); STEP(22); STEP(23);
      const bool nact = (sb + KCH <= SBMAX);
      if (nact) LD4(Av0, Av1, Av2, Av3, base0 + 256);   // next g0 (use next r=0)
      STEP(24); STEP(25); STEP(26); STEP(27); STEP(28); STEP(29); STEP(30); STEP(31);
      if (nact) {
        LD4(Bv0, Bv1, Bv2, Bv3, base0 + 320);           // next g1 (use next r=8)
        if (isCons) {                    // prefetch next boundary window (sentinel-guarded)
          int cn = sb + KCH + lane; cn = cn > LL ? LL : cn;
          pcurB = (int*)(gcons + cn);
          Bpre = __int_as_float(__hip_atomic_load(pcurB, __ATOMIC_RELAXED,
                                                  __HIP_MEMORY_SCOPE_AGENT));
        }
      }
      if (isProd) {                      // tail export: window [sb-95, sb-32], coalesced
        int ec = sb - 95 + lane;
        ec = ec < 0 ? 0 : (ec > LL ? LL : ec);
        __hip_atomic_store((int*)(gprod + ec), __float_as_int(bndX[4][ec + BOFF]),
                           __ATOMIC_RELAXED, __HIP_MEMORY_SCOPE_AGENT);
      }
    }
    __syncthreads();
  }

  if (isProd) {   // backstop: full boundary-row sweep (correctness safety net)
    for (int c0 = lane; c0 <= LL; c0 += 64)
      __hip_atomic_store((int*)(gprod + c0), __float_as_int(bndX[4][c0 + BOFF]),
                         __ATOMIC_RELAXED, __HIP_MEMORY_SCOPE_AGENT);
  }

  // final cell (1024,1024): WG3 wave 3 lane 63 at s = 1087 (chunk sb=1056, r=31)
  if (wg == 3 && t == NT - 1) wsf[bb] = costL + CLOG * __builtin_amdgcn_logf(lastmm);
}

__global__ void reduce_mean(const float* __restrict__ ws, float* __restrict__ out) {
  if (threadIdx.x == 0 && blockIdx.x == 0) {
    float s = 0.f;
    for (int i = 0; i < NB; ++i) s += ws[i];
    out[0] = s * (1.0f / NB);
  }
}

extern "C" void kernel_launch(void* const* d_in, const int* in_sizes, int n_in,
                              void* d_out, int out_size, void* d_ws, size_t ws_size,
                              hipStream_t stream) {
  const float* o  = (const float*)d_in[0];
  const float* tg = (const float*)d_in[1];
  float* ws  = (float*)d_ws;
  float* out = (float*)d_out;

  dtw_kernel<<<4 * NB, NT, 0, stream>>>(o, tg, ws);
  reduce_mean<<<1, 64, 0, stream>>>(ws, out);
}

// Round 10
// 100.625 us; speedup vs baseline: 9.6231x; 1.0213x over previous
//
#include <hip/hip_runtime.h>

#define LL    1024
#define NB    8
#define NT    256          // 4 waves per WG
#define KCH   32           // steps per chunk (polling/publish granularity)
#define SKEW  96           // intra-WG data skew = 64 rows + KCH
#define SBMAX 1056         // last chunk start (covers local steps up to 1087)
#define YTN   1536         // y-table entries (float2) per table
#define BROW  1160         // bndX row stride (floats)
#define BOFF  128          // col 0 of a boundary row at index BOFF
#define GBASE 64           // d_ws float offset of link regions
#define GSTR  1280         // per-link region stride (floats)
#define C10   14.426950408889634f        // 10*log2(e)
#define CLOG  (-0.069314718055994531f)   // -(ln2)/10
#define EPS3  1e-12f

// Soft-DTW in e-space (e = exp(-10*D)); 16 strips x 64 rows across 4 WGs/batch.
// Round 10 = round-7 per-cell machinery (proven bit-exact) with the per-chunk
// __syncthreads REMOVED: waves free-run, synchronized only by data flags.
//  - intra-WG: producer release-stores scnt[wv]=sb+32 after staging its chunk
//    (release's lgkmcnt(0) orders the ds_writes); consumer acquire-polls.
//  - inter-WG: round-7 sentinel/atomic link protocol, tail export + backstop.
// Each wave loops over exactly its own 34 active chunks (no idle iterations).

#define YB4(k) ((((k) >> 3) & 1)                                               \
    ? (((((k) & 7) >> 1) == 0) ? Bv0 : ((((k) & 7) >> 1) == 1) ? Bv1           \
                               : ((((k) & 7) >> 1) == 2) ? Bv2 : Bv3)          \
    : (((((k) & 7) >> 1) == 0) ? Av0 : ((((k) & 7) >> 1) == 1) ? Av1           \
                               : ((((k) & 7) >> 1) == 2) ? Av2 : Av3))
#define FPE(k) (((k) & 1) ? YB4(k).z : YB4(k).x)
#define FNE(k) (((k) & 1) ? YB4(k).w : YB4(k).y)

// Cell (lane+1, j) at local step s = lane + j; entry ji = s - lane + 256.
#define STEP(r) do {                                                           \
    const float fp_ = FPE(r);                                                  \
    const float fn_ = FNE(r);                                                  \
    const float dppv_ = __int_as_float(__builtin_amdgcn_update_dpp(            \
        0, __float_as_int(E1), 0x138, 0xf, 0xf, true)); /* wave_shr:1 */       \
    const float bvs_ = __int_as_float(                                         \
        __builtin_amdgcn_readlane(__float_as_int(B), (r)));                    \
    const float upa_ = isL0 ? bvs_ : dppv_;                                    \
    const float eca_ = fminf(EN0 * fp_, EP0 * fn_);                            \
    const float mma_ = fmaf(up_del + E1 + upa_, (1.f / 3.f), EPS3);            \
    const float nva_ = eca_ * mma_;                                            \
    wbase[(r)] = nva_;                                                         \
    E1 = nva_; up_del = upa_; lastmm = mma_;                                   \
  } while (0)

#define LD4(d0, d1, d2, d3, byteoff) do {                                      \
    const char* p_ = ytp + (byteoff);                                          \
    d0 = *(const float4*)(p_);                                                 \
    d1 = *(const float4*)(p_ + 16);                                            \
    d2 = *(const float4*)(p_ + 32);                                            \
    d3 = *(const float4*)(p_ + 48);                                            \
  } while (0)

__global__ __launch_bounds__(NT, 1) void dtw_kernel(const float* __restrict__ outp,
                                                    const float* __restrict__ tgtp,
                                                    float* __restrict__ wsf) {
  const int bb = blockIdx.x >> 2;      // batch
  const int wg = blockIdx.x & 3;       // quarter: rows 256*wg+1 .. 256*wg+256
  const int t = threadIdx.x;
  const int lane = t & 63;
  const int wvs = __builtin_amdgcn_readfirstlane(t >> 6);

  __shared__ float2 ytabA[YTN];       // (fp,fn) at slot ji        (even lanes)
  __shared__ float2 ytabB[YTN];       // (fp,fn) at slot ji - 1    (odd lanes)
  __shared__ float  bndX[5][BROW];    // 0-2: waves 0-2 boundaries; 3: zeros+seed; 4: wave-3 staging
  __shared__ float  dumpA[4][128];    // LDS sink for non-lane-63 staging writes
  __shared__ int    scnt[4];          // per-wave staged progress (chunk_start+32)

  {
    float4* za = (float4*)&ytabA[0];
    for (int i = t; i < (YTN * 2) / 4; i += NT) za[i] = make_float4(0.f, 0.f, 0.f, 0.f);
    float4* zb2 = (float4*)&ytabB[0];
    for (int i = t; i < (YTN * 2) / 4; i += NT) zb2[i] = make_float4(0.f, 0.f, 0.f, 0.f);
    float4* zb = (float4*)&bndX[0][0];
    for (int i = t; i < (5 * BROW) / 4; i += NT) zb[i] = make_float4(0.f, 0.f, 0.f, 0.f);
    if (t < 4) scnt[t] = 0;
  }
  __syncthreads();

  const float* xb = outp + (size_t)bb * LL * LL;
  const float* yb = tgtp + (size_t)bb * LL * LL;

  // my row: global row 256*wg + 64*wvs + lane + 1
  const float xd = xb[256 * wg + 64 * wvs + lane];
  const float EP0 = __builtin_amdgcn_exp2f( C10 * xd);
  const float EN0 = __builtin_amdgcn_exp2f(-C10 * xd);

  {
    const float4 yv = *(const float4*)(yb + 4 * t);
    const float yy[4] = {yv.x, yv.y, yv.z, yv.w};
#pragma unroll
    for (int q = 0; q < 4; ++q) {
      const int ji = (4 * t + 1 + q) + 256;          // j in [1,1024]
      const float2 v = make_float2(__builtin_amdgcn_exp2f( C10 * yy[q]),
                                   __builtin_amdgcn_exp2f(-C10 * yy[q]));
      ytabA[ji] = v;
      ytabB[ji - 1] = v;
    }
  }
  if (wg == 0 && t == 0) bndX[3][BOFF] = 1.0f;      // e[0,0] = 1 seed
  const float costL = (wg == 3 && t == NT - 1) ? fabsf(xd - yb[LL - 1]) : 0.f;
  __syncthreads();                                   // the ONLY barrier

  float E1 = 0.f, up_del = 0.f, lastmm = EPS3;
  float4 Av0, Av1, Av2, Av3;
  float4 Bv0 = make_float4(0.f, 0.f, 0.f, 0.f), Bv1 = Bv0, Bv2 = Bv0, Bv3 = Bv0;
  Av0 = Bv0; Av1 = Bv0; Av2 = Bv0; Av3 = Bv0;
  const bool isL0 = (lane == 0);
  const int wprev = (wvs == 0) ? 3 : (wvs - 1);
  const int wwr   = (wvs == 3) ? 4 : wvs;
  const bool isProd = (wg < 3) && (wvs == 3);
  const bool isCons = (wg > 0) && (wvs == 0);
  // per-lane y-table view: 16B-aligned for every lane via the dual table
  const char* ytp = (lane & 1) ? (const char*)ytabB : (const char*)ytabA;
  const int   loff = 8 * (((lane & 1) ? 255 : 256) - lane);

  float* gprod = wsf + GBASE + (bb * 3 + wg)     * GSTR + 128;  // valid when wg<3
  float* gcons = wsf + GBASE + (bb * 3 + wg - 1) * GSTR + 128;  // valid when wg>0

  float Bpre = 0.f;
  int*  pcurB = (int*)gcons;
  if (isCons) {
    // sentinel-fill our link region (robust to any initial / stale d_ws content)
    for (int c0 = lane; c0 <= LL; c0 += 64)
      __hip_atomic_store((int*)(gcons + c0), __float_as_int(-1.0f),
                         __ATOMIC_RELAXED, __HIP_MEMORY_SCOPE_AGENT);
    __threadfence();
  }

#pragma unroll 1
  for (int sb = 0; sb <= SBMAX; sb += KCH) {
    // ---- gate: wait until the up-neighbor boundary window [sb, sb+31] is staged
    float B;
    if (wvs != 0) {
      const int tgt = (sb + SKEW < SBMAX + KCH) ? (sb + SKEW) : (SBMAX + KCH);
      int guard = 0;
      while (__hip_atomic_load(&scnt[wvs - 1], __ATOMIC_ACQUIRE,
                               __HIP_MEMORY_SCOPE_WORKGROUP) < tgt &&
             ++guard < (1 << 20)) {}
      int colp = sb + lane; colp = colp > LL ? LL : colp;
      B = bndX[wprev][colp + BOFF];
    } else if (isCons) {
      if (sb == 0) {
        pcurB = (int*)(gcons + lane);
        Bpre = __int_as_float(__hip_atomic_load(pcurB, __ATOMIC_RELAXED,
                                                __HIP_MEMORY_SCOPE_AGENT));
      }
      float bv = Bpre;
      if (isL0 && sb == 0) bv = 0.f;                 // col 0 border: e = 0
      int tries = 0;
      while ((__ballot(bv < 0.f) & 0xffffffffull) && tries < (1 << 16)) {
        __builtin_amdgcn_s_sleep(2); ++tries;
        bv = __int_as_float(__hip_atomic_load(pcurB, __ATOMIC_RELAXED,
                                              __HIP_MEMORY_SCOPE_AGENT));
        if (isL0 && sb == 0) bv = 0.f;
      }
      B = bv;
    } else {
      int colp = sb + lane; colp = colp > LL ? LL : colp;
      B = bndX[wprev][colp + BOFF];                  // wg0 wave0: zeros + seed row
    }

    const int base0 = loff + 8 * sb;
    if (sb == 0) {                                   // first chunk: no prefetch cover
      LD4(Av0, Av1, Av2, Av3, base0);                // g0: entries 0..7
      LD4(Bv0, Bv1, Bv2, Bv3, base0 + 64);           // g1: entries 8..15
    }
    // staging: lane 63 -> boundary row (col sb+r-63 at index sb+65+r), else sink
    float* wbase = (lane == 63) ? &bndX[wwr][sb + 65] : &dumpA[wvs][lane];

    STEP(0); STEP(1); STEP(2); STEP(3); STEP(4); STEP(5); STEP(6); STEP(7);
    LD4(Av0, Av1, Av2, Av3, base0 + 128);            // g2: entries 16..23 (use r=16)
    STEP(8); STEP(9); STEP(10); STEP(11); STEP(12); STEP(13); STEP(14); STEP(15);
    LD4(Bv0, Bv1, Bv2, Bv3, base0 + 192);            // g3: entries 24..31 (use r=24)
    STEP(16); STEP(17); STEP(18); STEP(19); STEP(20); STEP(21); STEP(22); STEP(23);
    STEP(24); STEP(25); STEP(26); STEP(27); STEP(28); STEP(29); STEP(30); STEP(31);

    // ---- publish: release after the last staging ds_write
    if (wvs < 3 && lane == 63)
      __hip_atomic_store(&scnt[wvs], sb + KCH, __ATOMIC_RELEASE,
                         __HIP_MEMORY_SCOPE_WORKGROUP);
    if (isProd) {                                    // tail export [sb-95, sb-32]
      int ec = sb - 95 + lane;
      ec = ec < 0 ? 0 : (ec > LL ? LL : ec);
      __hip_atomic_store((int*)(gprod + ec), __float_as_int(bndX[4][ec + BOFF]),
                         __ATOMIC_RELAXED, __HIP_MEMORY_SCOPE_AGENT);
    }
    if (sb + KCH <= SBMAX) {                         // next-chunk prefetch
      LD4(Av0, Av1, Av2, Av3, base0 + 256);          // next g0 (use next r=0)
      LD4(Bv0, Bv1, Bv2, Bv3, base0 + 320);          // next g1 (use next r=8)
      if (isCons) {
        int cn = sb + KCH + lane; cn = cn > LL ? LL : cn;
        pcurB = (int*)(gcons + cn);
        Bpre = __int_as_float(__hip_atomic_load(pcurB, __ATOMIC_RELAXED,
                                                __HIP_MEMORY_SCOPE_AGENT));
      }
    }
  }

  if (isProd) {   // backstop: full boundary-row sweep (correctness safety net)
    for (int c0 = lane; c0 <= LL; c0 += 64)
      __hip_atomic_store((int*)(gprod + c0), __float_as_int(bndX[4][c0 + BOFF]),
                         __ATOMIC_RELAXED, __HIP_MEMORY_SCOPE_AGENT);
  }

  // final cell (1024,1024): WG3 wave 3 lane 63 at s = 1087 (chunk sb=1056, r=31)
  if (wg == 3 && t == NT - 1) wsf[bb] = costL + CLOG * __builtin_amdgcn_logf(lastmm);
}

__global__ void reduce_mean(const float* __restrict__ ws, float* __restrict__ out) {
  if (threadIdx.x == 0 && blockIdx.x == 0) {
    float s = 0.f;
    for (int i = 0; i < NB; ++i) s += ws[i];
    out[0] = s * (1.0f / NB);
  }
}

extern "C" void kernel_launch(void* const* d_in, const int* in_sizes, int n_in,
                              void* d_out, int out_size, void* d_ws, size_t ws_size,
                              hipStream_t stream) {
  const float* o  = (const float*)d_in[0];
  const float* tg = (const float*)d_in[1];
  float* ws  = (float*)d_ws;
  float* out = (float*)d_out;

  dtw_kernel<<<4 * NB, NT, 0, stream>>>(o, tg, ws);
  reduce_mean<<<1, 64, 0, stream>>>(ws, out);
}